// Round 1
// baseline (455.716 us; speedup 1.0000x reference)
//
#include <hip/hip_runtime.h>

// YOLO loss on MI355X. Layout:
//   prediction: (N, S, S, 90)  fp32, N=8192, S=7  -> 401408 cells x 90 ch
//   target:     (N, S, S, 85)  fp32               -> 401408 cells x 85 ch
// Output: 6 fp32 scalars (loss, loss_xy, loss_wh, loss_conf_obj, loss_conf_noobj, loss_class)
//
// Strategy: one wave (64 lanes) per cell, grid-stride. Lanes cover the 80-ch
// class SSE with coalesced loads (160 of 175 floats/cell = 91% of bytes).
// Lane 0 handles the 15 box/conf scalars (same cache lines -> ~free).
// 5 partial sums: per-lane acc -> wave shfl reduce -> LDS block reduce ->
// atomicAdd into d_ws[0..4]; tiny finalize kernel scales & writes d_out[0..5].

#define N_IMG 8192
#define NCELLS (N_IMG * 49)
constexpr float BSF = 8192.0f;

__device__ __forceinline__ void rel2abs(float x, float y, float w, float h,
                                        float fi, float fj,
                                        float& x1, float& y1, float& x2, float& y2) {
    float xc = (x + fj) / 7.0f;
    float yc = (y + fi) / 7.0f;
    float hw = w * 0.5f, hh = h * 0.5f;
    x1 = xc - hw; y1 = yc - hh; x2 = xc + hw; y2 = yc + hh;
}

__device__ __forceinline__ float iou_abs(float ax1, float ay1, float ax2, float ay2,
                                         float bx1, float by1, float bx2, float by2) {
    float iw = fminf(ax2, bx2) - fmaxf(ax1, bx1); iw = fmaxf(iw, 0.0f);
    float ih = fminf(ay2, by2) - fmaxf(ay1, by1); ih = fmaxf(ih, 0.0f);
    float inter  = iw * ih;
    float area_a = (ax2 - ax1) * (ay2 - ay1);
    float area_b = (bx2 - bx1) * (by2 - by1);
    return inter / (area_a + area_b - inter + 1e-6f);
}

__global__ __launch_bounds__(256) void yolo_main(const float* __restrict__ pred,
                                                 const float* __restrict__ tgt,
                                                 float* __restrict__ acc) {
    const int lane  = threadIdx.x & 63;
    const int wid   = threadIdx.x >> 6;
    const int gwave = (blockIdx.x * blockDim.x + threadIdx.x) >> 6;
    const int nwaves = (gridDim.x * blockDim.x) >> 6;

    float a_xy = 0.f, a_wh = 0.f, a_co = 0.f, a_cn = 0.f, a_cl = 0.f;

    for (int cell = gwave; cell < NCELLS; cell += nwaves) {
        const float* p = pred + (size_t)cell * 90;
        const float* t = tgt  + (size_t)cell * 85;

        // objectness (broadcast load: same address across all lanes)
        float tc   = t[4];
        float objf = (tc != 0.0f) ? 1.0f : 0.0f;

        // ---- class SSE: 80 channels, coalesced lane-per-channel ----
        // tgt classes t[5..84] vs pred classes p[10..89]
        float d0  = t[5 + lane] - p[10 + lane];
        float sse = d0 * d0;
        if (lane < 16) {
            float d1 = t[69 + lane] - p[74 + lane];
            sse += d1 * d1;
        }
        a_cl += objf * sse;

        // ---- box / conf terms: lane 0 only (15 scalars, lines already hot) ----
        if (lane == 0) {
            float tx = t[0], ty = t[1], tw = t[2], th = t[3];
            float p0x = p[0], p0y = p[1], p0w = p[2], p0h = p[3];
            float p1x = p[5], p1y = p[6], p1w = p[7], p1h = p[8];
            float pc  = p[9];   // pred_c = prediction[..., 4 + 5*(B-1)]

            int sij = cell % 49;
            float fi = (float)(sij / 7);   // row index (ii)
            float fj = (float)(sij % 7);   // col index (jj)

            float t1, t2, t3, t4, a1, a2, a3, a4, b1, b2, b3, b4;
            rel2abs(tx,  ty,  tw,  th,  fi, fj, t1, t2, t3, t4);
            rel2abs(p0x, p0y, p0w, p0h, fi, fj, a1, a2, a3, a4);
            rel2abs(p1x, p1y, p1w, p1h, fi, fj, b1, b2, b3, b4);

            float iou0 = iou_abs(t1, t2, t3, t4, a1, a2, a3, a4);
            float iou1 = iou_abs(t1, t2, t3, t4, b1, b2, b3, b4);

            // NOTE: reference: where(iou0 > iou1, pred[5:10], pred[0:5])
            bool sel = iou0 > iou1;
            float xh = sel ? p1x : p0x;
            float yh = sel ? p1y : p0y;
            float wh = sel ? p1w : p0w;
            float hh = sel ? p1h : p0h;

            float dx = tx - xh, dy = ty - yh;
            a_xy += objf * (dx * dx + dy * dy);

            float sw = sqrtf(tw) - sqrtf(fmaxf(wh, 0.0f));
            float sh = sqrtf(th) - sqrtf(fmaxf(hh, 0.0f));
            a_wh += objf * (sw * sw + sh * sh);

            float ce = tc - pc; ce *= ce;
            a_co += objf * ce;
            a_cn += (1.0f - objf) * ce;
        }
    }

    // ---- wave reduce (only a_cl is spread across lanes; others live in lane 0,
    //      but reducing all five keeps the code uniform and costs ~nothing) ----
    #pragma unroll
    for (int off = 32; off; off >>= 1) {
        a_xy += __shfl_down(a_xy, off, 64);
        a_wh += __shfl_down(a_wh, off, 64);
        a_co += __shfl_down(a_co, off, 64);
        a_cn += __shfl_down(a_cn, off, 64);
        a_cl += __shfl_down(a_cl, off, 64);
    }

    __shared__ float sm[4][5];
    if (lane == 0) {
        sm[wid][0] = a_xy; sm[wid][1] = a_wh; sm[wid][2] = a_co;
        sm[wid][3] = a_cn; sm[wid][4] = a_cl;
    }
    __syncthreads();
    if (threadIdx.x == 0) {
        float s0 = 0.f, s1 = 0.f, s2 = 0.f, s3 = 0.f, s4 = 0.f;
        #pragma unroll
        for (int w = 0; w < 4; ++w) {
            s0 += sm[w][0]; s1 += sm[w][1]; s2 += sm[w][2];
            s3 += sm[w][3]; s4 += sm[w][4];
        }
        atomicAdd(&acc[0], s0);
        atomicAdd(&acc[1], s1);
        atomicAdd(&acc[2], s2);
        atomicAdd(&acc[3], s3);
        atomicAdd(&acc[4], s4);
    }
}

__global__ void yolo_finalize(const float* __restrict__ acc, float* __restrict__ out) {
    if (threadIdx.x == 0 && blockIdx.x == 0) {
        float lxy = acc[0] / BSF;
        float lwh = acc[1] / BSF;
        float lco = acc[2] / BSF;
        float lcn = acc[3] / BSF;
        float lcl = acc[4] / BSF;
        out[0] = (5.0f * lxy + 5.0f * lwh + lco + 0.5f * lcn + lcl) / BSF;
        out[1] = lxy;
        out[2] = lwh;
        out[3] = lco;
        out[4] = lcn;
        out[5] = lcl;
    }
}

extern "C" void kernel_launch(void* const* d_in, const int* in_sizes, int n_in,
                              void* d_out, int out_size, void* d_ws, size_t ws_size,
                              hipStream_t stream) {
    const float* pred = (const float*)d_in[0];
    const float* tgt  = (const float*)d_in[1];
    float* out = (float*)d_out;
    float* acc = (float*)d_ws;   // 5 fp32 accumulators

    // d_ws is poisoned (0xAA) before every timed launch -> must zero here.
    hipMemsetAsync(acc, 0, 5 * sizeof(float), stream);

    // 2048 blocks x 256 threads = 8192 waves -> 49 cells/wave (grid-stride).
    yolo_main<<<2048, 256, 0, stream>>>(pred, tgt, acc);
    yolo_finalize<<<1, 64, 0, stream>>>(acc, out);
}

// Round 2
// 420.599 us; speedup vs baseline: 1.0835x; 1.0835x over previous
//
#include <hip/hip_runtime.h>

// YOLO loss on MI355X. Layout:
//   prediction: (N, S, S, 90)  fp32, N=8192, S=7  -> 401408 cells x 90 ch
//   target:     (N, S, S, 85)  fp32               -> 401408 cells x 85 ch
// Output: 6 fp32 scalars.
//
// R2 restructure: R1 was issue-bound (VALUBusy 62%, 571 GB/s) because the
// box/conf math ran under `if (lane==0)` -> ~70 wave-inst/cell at 1/64
// efficiency. Now each wave owns a TILE of 64 cells:
//   scalar phase: lane k does cell base+k's box/conf terms (all lanes useful)
//   class phase:  loop cc over tile, lanes = channels (coalesced), objf
//                 broadcast from lane cc via __shfl.
// 401408 cells / 64 = 6272 tiles exactly (no tail). 1568 blocks x 4 waves
// = 6272 waves -> one tile per wave.

#define N_IMG 8192
#define NCELLS (N_IMG * 49)
#define NTILES (NCELLS / 64)
constexpr float BSF = 8192.0f;

__device__ __forceinline__ void rel2abs(float x, float y, float w, float h,
                                        float fi, float fj,
                                        float& x1, float& y1, float& x2, float& y2) {
    float xc = (x + fj) / 7.0f;
    float yc = (y + fi) / 7.0f;
    float hw = w * 0.5f, hh = h * 0.5f;
    x1 = xc - hw; y1 = yc - hh; x2 = xc + hw; y2 = yc + hh;
}

__device__ __forceinline__ float iou_abs(float ax1, float ay1, float ax2, float ay2,
                                         float bx1, float by1, float bx2, float by2) {
    float iw = fminf(ax2, bx2) - fmaxf(ax1, bx1); iw = fmaxf(iw, 0.0f);
    float ih = fminf(ay2, by2) - fmaxf(ay1, by1); ih = fmaxf(ih, 0.0f);
    float inter  = iw * ih;
    float area_a = (ax2 - ax1) * (ay2 - ay1);
    float area_b = (bx2 - bx1) * (by2 - by1);
    return inter / (area_a + area_b - inter + 1e-6f);
}

__global__ __launch_bounds__(256) void yolo_main(const float* __restrict__ pred,
                                                 const float* __restrict__ tgt,
                                                 float* __restrict__ acc) {
    const int lane  = threadIdx.x & 63;
    const int wid   = threadIdx.x >> 6;
    const int gwave = (blockIdx.x * blockDim.x + threadIdx.x) >> 6;
    const int nwaves = (gridDim.x * blockDim.x) >> 6;

    float a_xy = 0.f, a_wh = 0.f, a_co = 0.f, a_cn = 0.f, a_cl = 0.f;

    for (int tile = gwave; tile < NTILES; tile += nwaves) {
        const int base = tile << 6;
        const int cell = base + lane;

        // ---------- scalar phase: lane k owns cell base+k ----------
        const float* t = tgt  + (size_t)cell * 85;
        const float* p = pred + (size_t)cell * 90;

        float tx = t[0], ty = t[1], tw = t[2], th = t[3], tc = t[4];
        float p0x = p[0], p0y = p[1], p0w = p[2], p0h = p[3];
        float p1x = p[5], p1y = p[6], p1w = p[7], p1h = p[8];
        float pc  = p[9];   // pred_c = prediction[..., 4 + 5*(B-1)]

        float objf = (tc != 0.0f) ? 1.0f : 0.0f;

        int sij = cell % 49;
        float fi = (float)(sij / 7);
        float fj = (float)(sij % 7);

        float t1, t2, t3, t4, a1, a2, a3, a4, b1, b2, b3, b4;
        rel2abs(tx,  ty,  tw,  th,  fi, fj, t1, t2, t3, t4);
        rel2abs(p0x, p0y, p0w, p0h, fi, fj, a1, a2, a3, a4);
        rel2abs(p1x, p1y, p1w, p1h, fi, fj, b1, b2, b3, b4);

        float iou0 = iou_abs(t1, t2, t3, t4, a1, a2, a3, a4);
        float iou1 = iou_abs(t1, t2, t3, t4, b1, b2, b3, b4);

        bool sel = iou0 > iou1;              // ref: where(iou0>iou1, pred[5:10], pred[0:5])
        float xh = sel ? p1x : p0x;
        float yh = sel ? p1y : p0y;
        float wh = sel ? p1w : p0w;
        float hh = sel ? p1h : p0h;

        float dx = tx - xh, dy = ty - yh;
        a_xy += objf * (dx * dx + dy * dy);

        float sw = sqrtf(tw) - sqrtf(fmaxf(wh, 0.0f));
        float sh = sqrtf(th) - sqrtf(fmaxf(hh, 0.0f));
        a_wh += objf * (sw * sw + sh * sh);

        float ce = tc - pc; ce *= ce;
        a_co += objf * ce;
        a_cn += (1.0f - objf) * ce;

        // ---------- class phase: loop over tile cells, lane = channel ----------
        const float* tb = tgt  + (size_t)base * 85 + 5;   // classes of cell base
        const float* pb = pred + (size_t)base * 90 + 10;

        for (int cc = 0; cc < 64; ++cc) {
            float of = __shfl(objf, cc, 64);   // objf of cell base+cc
            const float* tt = tb + cc * 85;
            const float* pp = pb + cc * 90;
            float d0 = tt[lane] - pp[lane];
            float s  = d0 * d0;
            if (lane < 16) {
                float d1 = tt[64 + lane] - pp[64 + lane];
                s += d1 * d1;
            }
            a_cl += of * s;
        }
    }

    // ---------- wave reduce ----------
    #pragma unroll
    for (int off = 32; off; off >>= 1) {
        a_xy += __shfl_down(a_xy, off, 64);
        a_wh += __shfl_down(a_wh, off, 64);
        a_co += __shfl_down(a_co, off, 64);
        a_cn += __shfl_down(a_cn, off, 64);
        a_cl += __shfl_down(a_cl, off, 64);
    }

    __shared__ float sm[4][5];
    if (lane == 0) {
        sm[wid][0] = a_xy; sm[wid][1] = a_wh; sm[wid][2] = a_co;
        sm[wid][3] = a_cn; sm[wid][4] = a_cl;
    }
    __syncthreads();
    if (threadIdx.x == 0) {
        float s0 = 0.f, s1 = 0.f, s2 = 0.f, s3 = 0.f, s4 = 0.f;
        #pragma unroll
        for (int w = 0; w < 4; ++w) {
            s0 += sm[w][0]; s1 += sm[w][1]; s2 += sm[w][2];
            s3 += sm[w][3]; s4 += sm[w][4];
        }
        atomicAdd(&acc[0], s0);
        atomicAdd(&acc[1], s1);
        atomicAdd(&acc[2], s2);
        atomicAdd(&acc[3], s3);
        atomicAdd(&acc[4], s4);
    }
}

__global__ void yolo_finalize(const float* __restrict__ acc, float* __restrict__ out) {
    if (threadIdx.x == 0 && blockIdx.x == 0) {
        float lxy = acc[0] / BSF;
        float lwh = acc[1] / BSF;
        float lco = acc[2] / BSF;
        float lcn = acc[3] / BSF;
        float lcl = acc[4] / BSF;
        out[0] = (5.0f * lxy + 5.0f * lwh + lco + 0.5f * lcn + lcl) / BSF;
        out[1] = lxy;
        out[2] = lwh;
        out[3] = lco;
        out[4] = lcn;
        out[5] = lcl;
    }
}

extern "C" void kernel_launch(void* const* d_in, const int* in_sizes, int n_in,
                              void* d_out, int out_size, void* d_ws, size_t ws_size,
                              hipStream_t stream) {
    const float* pred = (const float*)d_in[0];
    const float* tgt  = (const float*)d_in[1];
    float* out = (float*)d_out;
    float* acc = (float*)d_ws;   // 5 fp32 accumulators

    // d_ws is poisoned (0xAA) before every timed launch -> must zero here.
    hipMemsetAsync(acc, 0, 5 * sizeof(float), stream);

    // 1568 blocks x 4 waves = 6272 waves -> exactly one 64-cell tile per wave.
    yolo_main<<<1568, 256, 0, stream>>>(pred, tgt, acc);
    yolo_finalize<<<1, 64, 0, stream>>>(acc, out);
}

// Round 3
// 390.081 us; speedup vs baseline: 1.1683x; 1.0782x over previous
//
#include <hip/hip_runtime.h>

// YOLO loss on MI355X. Layout:
//   prediction: (N, S, S, 90)  fp32, N=8192, S=7  -> 401408 cells x 90 ch
//   target:     (N, S, S, 85)  fp32               -> 401408 cells x 85 ch
// Output: 6 fp32 scalars.
//
// R3: R2 was memory-LATENCY bound (VALUBusy 3%, 876 GB/s, VGPR=28 -> no ILP
// in the 4B-load class loop). Now each block stages a 64-cell tile into LDS
// via flat float4 loads (16B/lane coalesced, ~11 independent loads/thread in
// flight), then computes from LDS:
//   wave 0  : box/conf for all 64 cells (lane = cell)
//   waves1-3: class SSE, 27/27/26 channels each, all 64 cells (lane = cell)
// LDS 44.8 KB/block -> 3 blocks/CU; inter-block overlap hides barriers.
// 1568 blocks x 4 tiles = 6272 tiles = 401408 cells exactly.

#define NCELLS (8192 * 49)
#define NTILES (NCELLS / 64)          // 6272
#define NBLOCKS (NTILES / 4)          // 1568
constexpr float BSF = 8192.0f;

__device__ __forceinline__ void rel2abs(float x, float y, float w, float h,
                                        float fi, float fj,
                                        float& x1, float& y1, float& x2, float& y2) {
    float xc = (x + fj) / 7.0f;
    float yc = (y + fi) / 7.0f;
    float hw = w * 0.5f, hh = h * 0.5f;
    x1 = xc - hw; y1 = yc - hh; x2 = xc + hw; y2 = yc + hh;
}

__device__ __forceinline__ float iou_abs(float ax1, float ay1, float ax2, float ay2,
                                         float bx1, float by1, float bx2, float by2) {
    float iw = fminf(ax2, bx2) - fmaxf(ax1, bx1); iw = fmaxf(iw, 0.0f);
    float ih = fminf(ay2, by2) - fmaxf(ay1, by1); ih = fmaxf(ih, 0.0f);
    float inter  = iw * ih;
    float area_a = (ax2 - ax1) * (ay2 - ay1);
    float area_b = (bx2 - bx1) * (by2 - by1);
    return inter / (area_a + area_b - inter + 1e-6f);
}

__global__ __launch_bounds__(256) void yolo_main(const float* __restrict__ pred,
                                                 const float* __restrict__ tgt,
                                                 float* __restrict__ acc) {
    // Flat tile buffers: tgt 64*85=5440 floats, pred 64*90=5760 floats.
    __shared__ float t_s[5440];
    __shared__ float p_s[5760];
    __shared__ float smr[4 * 5];

    const int tid  = threadIdx.x;
    const int lane = tid & 63;
    const int wid  = tid >> 6;

    float a_xy = 0.f, a_wh = 0.f, a_co = 0.f, a_cn = 0.f, a_cl = 0.f;

    const int tile0 = blockIdx.x * 4;

    for (int it = 0; it < 4; ++it) {
        const int tile = tile0 + it;
        const int base = tile << 6;          // first cell of tile

        // ---------- stage: flat float4 copy, fully coalesced ----------
        // tgt tile byte offset = tile*21760 (16B-aligned); pred = tile*23040.
        const float4* gt = (const float4*)(tgt  + (size_t)base * 85);   // 1360 f4
        const float4* gp = (const float4*)(pred + (size_t)base * 90);   // 1440 f4

        float4 vt[6], vp[6];
        #pragma unroll
        for (int i = 0; i < 5; ++i) vt[i] = gt[tid + 256 * i];
        if (tid < 80)  vt[5] = gt[tid + 1280];
        #pragma unroll
        for (int i = 0; i < 5; ++i) vp[i] = gp[tid + 256 * i];
        if (tid < 160) vp[5] = gp[tid + 1280];

        float4* st = (float4*)t_s;
        float4* sp = (float4*)p_s;
        #pragma unroll
        for (int i = 0; i < 5; ++i) st[tid + 256 * i] = vt[i];
        if (tid < 80)  st[tid + 1280] = vt[5];
        #pragma unroll
        for (int i = 0; i < 5; ++i) sp[tid + 256 * i] = vp[i];
        if (tid < 160) sp[tid + 1280] = vp[5];

        __syncthreads();

        // ---------- compute from LDS (lane = cell within tile) ----------
        const float* tr = t_s + 85 * lane;
        const float* pr = p_s + 90 * lane;

        if (wid == 0) {
            // box + conf terms for cell base+lane
            float tx = tr[0], ty = tr[1], tw = tr[2], th = tr[3], tc = tr[4];
            float p0x = pr[0], p0y = pr[1], p0w = pr[2], p0h = pr[3];
            float p1x = pr[5], p1y = pr[6], p1w = pr[7], p1h = pr[8];
            float pc  = pr[9];                 // pred_c = prediction[..., 9]

            float objf = (tc != 0.0f) ? 1.0f : 0.0f;

            int cell = base + lane;
            int sij  = cell % 49;
            float fi = (float)(sij / 7);
            float fj = (float)(sij % 7);

            float t1, t2, t3, t4, a1, a2, a3, a4, b1, b2, b3, b4;
            rel2abs(tx,  ty,  tw,  th,  fi, fj, t1, t2, t3, t4);
            rel2abs(p0x, p0y, p0w, p0h, fi, fj, a1, a2, a3, a4);
            rel2abs(p1x, p1y, p1w, p1h, fi, fj, b1, b2, b3, b4);

            float iou0 = iou_abs(t1, t2, t3, t4, a1, a2, a3, a4);
            float iou1 = iou_abs(t1, t2, t3, t4, b1, b2, b3, b4);

            bool sel = iou0 > iou1;   // ref: where(iou0>iou1, pred[5:10], pred[0:5])
            float xh = sel ? p1x : p0x;
            float yh = sel ? p1y : p0y;
            float wh = sel ? p1w : p0w;
            float hh = sel ? p1h : p0h;

            float dx = tx - xh, dy = ty - yh;
            a_xy += objf * (dx * dx + dy * dy);

            float sw = sqrtf(tw) - sqrtf(fmaxf(wh, 0.0f));
            float sh = sqrtf(th) - sqrtf(fmaxf(hh, 0.0f));
            a_wh += objf * (sw * sw + sh * sh);

            float ce = tc - pc; ce *= ce;
            a_co += objf * ce;
            a_cn += (1.0f - objf) * ce;
        } else {
            // class SSE: wave w covers channels [c0, c1) for all 64 cells
            float objf = (tr[4] != 0.0f) ? 1.0f : 0.0f;
            const int c0 = (wid == 1) ? 0  : (wid == 2) ? 27 : 54;
            const int c1 = (wid == 1) ? 27 : (wid == 2) ? 54 : 80;
            float s = 0.f;
            #pragma unroll 9
            for (int ch = c0; ch < c1; ++ch) {
                float d = tr[5 + ch] - pr[10 + ch];
                s += d * d;
            }
            a_cl += objf * s;
        }
        __syncthreads();   // protect LDS before next tile's staging
    }

    // ---------- reduce: wave shfl -> LDS -> block atomics ----------
    #pragma unroll
    for (int off = 32; off; off >>= 1) {
        a_xy += __shfl_down(a_xy, off, 64);
        a_wh += __shfl_down(a_wh, off, 64);
        a_co += __shfl_down(a_co, off, 64);
        a_cn += __shfl_down(a_cn, off, 64);
        a_cl += __shfl_down(a_cl, off, 64);
    }
    if (lane == 0) {
        smr[wid * 5 + 0] = a_xy; smr[wid * 5 + 1] = a_wh; smr[wid * 5 + 2] = a_co;
        smr[wid * 5 + 3] = a_cn; smr[wid * 5 + 4] = a_cl;
    }
    __syncthreads();
    if (tid == 0) {
        float s0 = 0.f, s1 = 0.f, s2 = 0.f, s3 = 0.f, s4 = 0.f;
        #pragma unroll
        for (int w = 0; w < 4; ++w) {
            s0 += smr[w * 5 + 0]; s1 += smr[w * 5 + 1]; s2 += smr[w * 5 + 2];
            s3 += smr[w * 5 + 3]; s4 += smr[w * 5 + 4];
        }
        atomicAdd(&acc[0], s0);
        atomicAdd(&acc[1], s1);
        atomicAdd(&acc[2], s2);
        atomicAdd(&acc[3], s3);
        atomicAdd(&acc[4], s4);
    }
}

__global__ void yolo_finalize(const float* __restrict__ acc, float* __restrict__ out) {
    if (threadIdx.x == 0 && blockIdx.x == 0) {
        float lxy = acc[0] / BSF;
        float lwh = acc[1] / BSF;
        float lco = acc[2] / BSF;
        float lcn = acc[3] / BSF;
        float lcl = acc[4] / BSF;
        out[0] = (5.0f * lxy + 5.0f * lwh + lco + 0.5f * lcn + lcl) / BSF;
        out[1] = lxy;
        out[2] = lwh;
        out[3] = lco;
        out[4] = lcn;
        out[5] = lcl;
    }
}

extern "C" void kernel_launch(void* const* d_in, const int* in_sizes, int n_in,
                              void* d_out, int out_size, void* d_ws, size_t ws_size,
                              hipStream_t stream) {
    const float* pred = (const float*)d_in[0];
    const float* tgt  = (const float*)d_in[1];
    float* out = (float*)d_out;
    float* acc = (float*)d_ws;   // 5 fp32 accumulators

    // d_ws is poisoned (0xAA) before every timed launch -> must zero here.
    hipMemsetAsync(acc, 0, 5 * sizeof(float), stream);

    // 1568 blocks x 4 tiles each = 6272 tiles (exact).
    yolo_main<<<NBLOCKS, 256, 0, stream>>>(pred, tgt, acc);
    yolo_finalize<<<1, 64, 0, stream>>>(acc, out);
}

// Round 4
// 334.549 us; speedup vs baseline: 1.3622x; 1.1660x over previous
//
#include <hip/hip_runtime.h>

// YOLO loss on MI355X. Layout:
//   prediction: (N, S, S, 90)  fp32, N=8192, S=7  -> 401408 cells x 90 ch
//   target:     (N, S, S, 85)  fp32               -> 401408 cells x 85 ch
// Output: 6 fp32 scalars.
//
// R4: R3's float4 vt[6]/vp[6] staging arrays were demoted to SCRATCH
// (VGPR=68, WRITE_SIZE 265 MB = tile bytes -> HBM round trip per tile).
// Fix: stage global->LDS directly with __builtin_amdgcn_global_load_lds
// width=16 (async DMA, no VGPR/scratch round trip; m97-verified path).
// Layout is flat-contiguous so the wave-uniform-base + lane*16 LDS-dest
// rule is satisfied, including the partial-wave tails.
//   wave 0  : box/conf for all 64 cells (lane = cell)
//   waves1-3: class SSE, 27/27/26 channels each, all 64 cells (lane = cell)
// LDS 44.8 KB/block -> 3 blocks/CU; inter-block overlap hides barriers.
// 1568 blocks x 4 tiles = 6272 tiles = 401408 cells exactly.

#define NCELLS (8192 * 49)
#define NTILES (NCELLS / 64)          // 6272
#define NBLOCKS (NTILES / 4)          // 1568
constexpr float BSF = 8192.0f;

__device__ __forceinline__ void g2lds16(const float* g, float* s) {
    __builtin_amdgcn_global_load_lds(
        (const __attribute__((address_space(1))) void*)g,
        (__attribute__((address_space(3))) void*)s,
        16, 0, 0);
}

__device__ __forceinline__ void rel2abs(float x, float y, float w, float h,
                                        float fi, float fj,
                                        float& x1, float& y1, float& x2, float& y2) {
    float xc = (x + fj) / 7.0f;
    float yc = (y + fi) / 7.0f;
    float hw = w * 0.5f, hh = h * 0.5f;
    x1 = xc - hw; y1 = yc - hh; x2 = xc + hw; y2 = yc + hh;
}

__device__ __forceinline__ float iou_abs(float ax1, float ay1, float ax2, float ay2,
                                         float bx1, float by1, float bx2, float by2) {
    float iw = fminf(ax2, bx2) - fmaxf(ax1, bx1); iw = fmaxf(iw, 0.0f);
    float ih = fminf(ay2, by2) - fmaxf(ay1, by1); ih = fmaxf(ih, 0.0f);
    float inter  = iw * ih;
    float area_a = (ax2 - ax1) * (ay2 - ay1);
    float area_b = (bx2 - bx1) * (by2 - by1);
    return inter / (area_a + area_b - inter + 1e-6f);
}

__global__ __launch_bounds__(256) void yolo_main(const float* __restrict__ pred,
                                                 const float* __restrict__ tgt,
                                                 float* __restrict__ acc) {
    // Flat tile buffers: tgt 64*85=5440 floats, pred 64*90=5760 floats.
    __shared__ __align__(16) float t_s[5440];
    __shared__ __align__(16) float p_s[5760];
    __shared__ float smr[4 * 5];

    const int tid  = threadIdx.x;
    const int lane = tid & 63;
    const int wid  = tid >> 6;

    float a_xy = 0.f, a_wh = 0.f, a_co = 0.f, a_cn = 0.f, a_cl = 0.f;

    const int tile0 = blockIdx.x * 4;

    for (int it = 0; it < 4; ++it) {
        const int tile = tile0 + it;
        const int base = tile << 6;          // first cell of tile

        // ---------- stage: direct global->LDS DMA, 16 B/lane ----------
        // tgt tile: 1360 float4 (5x256 + 80); pred tile: 1440 float4 (5x256 + 160).
        const float* gtb = tgt  + (size_t)base * 85;
        const float* gpb = pred + (size_t)base * 90;

        #pragma unroll
        for (int i = 0; i < 5; ++i) {
            int idx = 4 * (tid + 256 * i);
            g2lds16(gtb + idx, t_s + idx);
        }
        if (tid < 80) {
            int idx = 4 * (tid + 1280);
            g2lds16(gtb + idx, t_s + idx);
        }
        #pragma unroll
        for (int i = 0; i < 5; ++i) {
            int idx = 4 * (tid + 256 * i);
            g2lds16(gpb + idx, p_s + idx);
        }
        if (tid < 160) {
            int idx = 4 * (tid + 1280);
            g2lds16(gpb + idx, p_s + idx);
        }

        __syncthreads();   // compiler drains vmcnt before the barrier

        // ---------- compute from LDS (lane = cell within tile) ----------
        const float* tr = t_s + 85 * lane;
        const float* pr = p_s + 90 * lane;

        if (wid == 0) {
            // box + conf terms for cell base+lane
            float tx = tr[0], ty = tr[1], tw = tr[2], th = tr[3], tc = tr[4];
            float p0x = pr[0], p0y = pr[1], p0w = pr[2], p0h = pr[3];
            float p1x = pr[5], p1y = pr[6], p1w = pr[7], p1h = pr[8];
            float pc  = pr[9];                 // pred_c = prediction[..., 9]

            float objf = (tc != 0.0f) ? 1.0f : 0.0f;

            int cell = base + lane;
            int sij  = cell % 49;
            float fi = (float)(sij / 7);
            float fj = (float)(sij % 7);

            float t1, t2, t3, t4, a1, a2, a3, a4, b1, b2, b3, b4;
            rel2abs(tx,  ty,  tw,  th,  fi, fj, t1, t2, t3, t4);
            rel2abs(p0x, p0y, p0w, p0h, fi, fj, a1, a2, a3, a4);
            rel2abs(p1x, p1y, p1w, p1h, fi, fj, b1, b2, b3, b4);

            float iou0 = iou_abs(t1, t2, t3, t4, a1, a2, a3, a4);
            float iou1 = iou_abs(t1, t2, t3, t4, b1, b2, b3, b4);

            bool sel = iou0 > iou1;   // ref: where(iou0>iou1, pred[5:10], pred[0:5])
            float xh = sel ? p1x : p0x;
            float yh = sel ? p1y : p0y;
            float wh = sel ? p1w : p0w;
            float hh = sel ? p1h : p0h;

            float dx = tx - xh, dy = ty - yh;
            a_xy += objf * (dx * dx + dy * dy);

            float sw = sqrtf(tw) - sqrtf(fmaxf(wh, 0.0f));
            float sh = sqrtf(th) - sqrtf(fmaxf(hh, 0.0f));
            a_wh += objf * (sw * sw + sh * sh);

            float ce = tc - pc; ce *= ce;
            a_co += objf * ce;
            a_cn += (1.0f - objf) * ce;
        } else {
            // class SSE: wave w covers channels [c0, c1) for all 64 cells
            float objf = (tr[4] != 0.0f) ? 1.0f : 0.0f;
            const int c0 = (wid == 1) ? 0  : (wid == 2) ? 27 : 54;
            const int c1 = (wid == 1) ? 27 : (wid == 2) ? 54 : 80;
            float s = 0.f;
            #pragma unroll 9
            for (int ch = c0; ch < c1; ++ch) {
                float d = tr[5 + ch] - pr[10 + ch];
                s += d * d;
            }
            a_cl += objf * s;
        }
        __syncthreads();   // protect LDS before next tile's staging
    }

    // ---------- reduce: wave shfl -> LDS -> block atomics ----------
    #pragma unroll
    for (int off = 32; off; off >>= 1) {
        a_xy += __shfl_down(a_xy, off, 64);
        a_wh += __shfl_down(a_wh, off, 64);
        a_co += __shfl_down(a_co, off, 64);
        a_cn += __shfl_down(a_cn, off, 64);
        a_cl += __shfl_down(a_cl, off, 64);
    }
    if (lane == 0) {
        smr[wid * 5 + 0] = a_xy; smr[wid * 5 + 1] = a_wh; smr[wid * 5 + 2] = a_co;
        smr[wid * 5 + 3] = a_cn; smr[wid * 5 + 4] = a_cl;
    }
    __syncthreads();
    if (tid == 0) {
        float s0 = 0.f, s1 = 0.f, s2 = 0.f, s3 = 0.f, s4 = 0.f;
        #pragma unroll
        for (int w = 0; w < 4; ++w) {
            s0 += smr[w * 5 + 0]; s1 += smr[w * 5 + 1]; s2 += smr[w * 5 + 2];
            s3 += smr[w * 5 + 3]; s4 += smr[w * 5 + 4];
        }
        atomicAdd(&acc[0], s0);
        atomicAdd(&acc[1], s1);
        atomicAdd(&acc[2], s2);
        atomicAdd(&acc[3], s3);
        atomicAdd(&acc[4], s4);
    }
}

__global__ void yolo_finalize(const float* __restrict__ acc, float* __restrict__ out) {
    if (threadIdx.x == 0 && blockIdx.x == 0) {
        float lxy = acc[0] / BSF;
        float lwh = acc[1] / BSF;
        float lco = acc[2] / BSF;
        float lcn = acc[3] / BSF;
        float lcl = acc[4] / BSF;
        out[0] = (5.0f * lxy + 5.0f * lwh + lco + 0.5f * lcn + lcl) / BSF;
        out[1] = lxy;
        out[2] = lwh;
        out[3] = lco;
        out[4] = lcn;
        out[5] = lcl;
    }
}

extern "C" void kernel_launch(void* const* d_in, const int* in_sizes, int n_in,
                              void* d_out, int out_size, void* d_ws, size_t ws_size,
                              hipStream_t stream) {
    const float* pred = (const float*)d_in[0];
    const float* tgt  = (const float*)d_in[1];
    float* out = (float*)d_out;
    float* acc = (float*)d_ws;   // 5 fp32 accumulators

    // d_ws is poisoned (0xAA) before every timed launch -> must zero here.
    hipMemsetAsync(acc, 0, 5 * sizeof(float), stream);

    // 1568 blocks x 4 tiles each = 6272 tiles (exact).
    yolo_main<<<NBLOCKS, 256, 0, stream>>>(pred, tgt, acc);
    yolo_finalize<<<1, 64, 0, stream>>>(acc, out);
}